// Round 6
// baseline (208.838 us; speedup 1.0000x reference)
//
#include <hip/hip_runtime.h>
#include <hip/hip_bf16.h>
#include <hip/hip_cooperative_groups.h>
#include <math.h>

namespace cg = cooperative_groups;

#define N_NODES 2048
#define IN_F    1024
#define NH      8
#define HF      32
#define OUTF    256   // NH*HF
#define JSPLIT  4
#define JR      (N_NODES / JSPLIT)   // 512 j's per attention job
#define NBLK    256                  // cooperative-safe: 1 block/CU
#define NTHR    512

typedef __attribute__((ext_vector_type(8))) short short8;
typedef __attribute__((ext_vector_type(4))) float f32x4;

__device__ __forceinline__ short f2bf(float x) {   // fp32 -> bf16 bits, RNE
  unsigned u = __float_as_uint(x);
  return (short)((u + 0x7FFFu + ((u >> 16) & 1u)) >> 16);
}
__device__ __forceinline__ float bf2f(short b) {
  return __uint_as_float(((unsigned)(unsigned short)b) << 16);
}

// ===================== Phase 1: prep (split h/W, pack adj) =================
__device__ __forceinline__ void phase_prep(int bid, int tid,
    const float* __restrict__ h, const int* __restrict__ adj,
    const float* __restrict__ W, short* __restrict__ h_hi,
    short* __restrict__ h_lo, short* __restrict__ wt_hi,
    short* __restrict__ wt_lo, unsigned* __restrict__ bits) {
  const int T = bid * NTHR + tid;           // 0 .. 131071
  #pragma unroll
  for (int rep = 0; rep < 2; ++rep) {       // 262144 h-units of 8 floats
    const int u = T + rep * (NBLK * NTHR);
    const float4 v0 = *(const float4*)(h + u * 8);
    const float4 v1 = *(const float4*)(h + u * 8 + 4);
    const float x[8] = {v0.x, v0.y, v0.z, v0.w, v1.x, v1.y, v1.z, v1.w};
    short8 hi, lo;
    #pragma unroll
    for (int j = 0; j < 8; ++j) {
      const short hb = f2bf(x[j]);
      hi[j] = hb;
      lo[j] = f2bf(x[j] - bf2f(hb));
    }
    *(short8*)(h_hi + u * 8) = hi;
    *(short8*)(h_lo + u * 8) = lo;
  }
  if (T < (OUTF * IN_F / 8)) {              // 32768 W units (transpose+split)
    const int n = T >> 7, kg = T & 127;
    short8 hi, lo;
    #pragma unroll
    for (int j = 0; j < 8; ++j) {
      const float x = W[(kg * 8 + j) * OUTF + n];
      const short hb = f2bf(x);
      hi[j] = hb;
      lo[j] = f2bf(x - bf2f(hb));
    }
    *(short8*)(wt_hi + n * IN_F + kg * 8) = hi;
    *(short8*)(wt_lo + n * IN_F + kg * 8) = lo;
  }
  {                                         // 131072 bit-words, one each
    const int4* p = (const int4*)(adj + (T >> 6) * N_NODES + (T & 63) * 32);
    unsigned wbits = 0;
    #pragma unroll
    for (int v = 0; v < 8; ++v) {
      const int4 x = p[v];
      wbits |= (x.x != 0 ? 1u : 0u) << (4 * v + 0);
      wbits |= (x.y != 0 ? 1u : 0u) << (4 * v + 1);
      wbits |= (x.z != 0 ? 1u : 0u) << (4 * v + 2);
      wbits |= (x.w != 0 ? 1u : 0u) << (4 * v + 3);
    }
    bits[T] = wbits;
  }
}

// ===================== Phase 2: g = h@W via split-bf16 MFMA, full K ========
// 2048 waves = 128 m16 x 16 n16; wave = 16x16 out tile, K=1024.
__device__ __forceinline__ void phase_gemm(int bid, int tid,
    const short* __restrict__ h_hi, const short* __restrict__ h_lo,
    const short* __restrict__ wt_hi, const short* __restrict__ wt_lo,
    float* __restrict__ gp) {
  const int Wv = bid * 8 + (tid >> 6);
  const int l = tid & 63;
  const int il = l & 15, q = l >> 4;
  const int m16 = Wv >> 4, n16 = Wv & 15;

  const short* ah = h_hi + (m16 * 16 + il) * IN_F;
  const short* al = h_lo + (m16 * 16 + il) * IN_F;
  const short* bh = wt_hi + (n16 * 16 + il) * IN_F;
  const short* bl = wt_lo + (n16 * 16 + il) * IN_F;

  f32x4 acc = {0.f, 0.f, 0.f, 0.f};
  #pragma unroll 4
  for (int k0 = 0; k0 < IN_F; k0 += 32) {
    const short8 a_h = *(const short8*)(ah + k0 + 8 * q);
    const short8 a_l = *(const short8*)(al + k0 + 8 * q);
    const short8 b_h = *(const short8*)(bh + k0 + 8 * q);
    const short8 b_l = *(const short8*)(bl + k0 + 8 * q);
    acc = __builtin_amdgcn_mfma_f32_16x16x32_bf16(a_h, b_h, acc, 0, 0, 0);
    acc = __builtin_amdgcn_mfma_f32_16x16x32_bf16(a_h, b_l, acc, 0, 0, 0);
    acc = __builtin_amdgcn_mfma_f32_16x16x32_bf16(a_l, b_h, acc, 0, 0, 0);
  }
  #pragma unroll
  for (int r = 0; r < 4; ++r)                 // D: row=4q+r, col=il
    gp[(m16 * 16 + 4 * q + r) * OUTF + n16 * 16 + il] = acc[r];
}

// ===================== Phase 3: scores + gt transpose ======================
// block = 8 node rows; all heads. tile LDS = 8x256 fp32.
__device__ __forceinline__ void phase_scores(int bid, int tid,
    const float* __restrict__ gp, const float* __restrict__ a,
    short* __restrict__ gt, float* __restrict__ s_l,
    float* __restrict__ s_r_t) {
  __shared__ float tile[8][260];
  const int i0 = bid * 8;
  {
    const int row = tid >> 6, c4 = (tid & 63) * 4;
    *(float4*)&tile[row][c4] = *(const float4*)(gp + (i0 + row) * OUTF + c4);
  }
  __syncthreads();
  if (tid < 64) {
    const int row = tid >> 3, hh = tid & 7;
    float sl = 0.f, sr = 0.f;
    #pragma unroll
    for (int f = 0; f < HF; ++f) {
      const float gv = tile[row][hh * HF + f];
      sl = fmaf(gv, a[f], sl);
      sr = fmaf(gv, a[HF + f], sr);
    }
    s_l[(i0 + row) * NH + hh] = sl;
    s_r_t[hh * N_NODES + i0 + row] = sr;
  }
  if (tid < 256) {
    const int hh = tid >> 5, f = tid & 31;
    short8 o;
    #pragma unroll
    for (int rr = 0; rr < 8; ++rr) o[rr] = f2bf(tile[rr][hh * HF + f]);
    *(short8*)(gt + (hh * HF + f) * N_NODES + i0) = o;
  }
}

// ===================== Phase 4: MFMA attention partials ====================
// job in [0,512) = (i-tile of 16) x (jsplit). wave = head.
__device__ __forceinline__ void phase_attn(int job, int tid,
    const unsigned* __restrict__ bits, const short* __restrict__ gt,
    const float* __restrict__ s_l, const float* __restrict__ s_r_t,
    float* __restrict__ pout, float* __restrict__ pl) {
  const int i0 = (job >> 2) * 16;
  const int split = job & 3;
  const int hh = tid >> 6;
  const int l = tid & 63;
  const int il = l & 15;
  const int q = l >> 4;

  const float slv = s_l[(i0 + il) * NH + hh];
  const unsigned* bitrow = bits + (i0 + il) * 64;
  const float* srh = s_r_t + hh * N_NODES;
  const short* g0p = gt + (hh * HF + il) * N_NODES;
  const short* g1p = gt + (hh * HF + 16 + il) * N_NODES;

  f32x4 acc0 = {0.f, 0.f, 0.f, 0.f};
  f32x4 acc1 = {0.f, 0.f, 0.f, 0.f};
  float denom = 0.f;

  const int jbase = split * JR;
  for (int j0 = jbase; j0 < jbase + JR; j0 += 32) {
    const unsigned word = bitrow[j0 >> 5];
    const float4 sra = *(const float4*)(srh + j0 + 8 * q);
    const float4 srb = *(const float4*)(srh + j0 + 8 * q + 4);
    const float sr_[8] = {sra.x, sra.y, sra.z, sra.w, srb.x, srb.y, srb.z, srb.w};
    short8 afrag;
    #pragma unroll
    for (int r = 0; r < 8; ++r) {
      float e = slv + sr_[r];
      e = fmaxf(e, 0.2f * e);                               // leaky relu
      const float wv = ((word >> (8 * q + r)) & 1u) ? __expf(e) : 0.f;
      const short wb = f2bf(wv);
      afrag[r] = wb;
      denom += bf2f(wb);     // denom consistent with bf16 numerator
    }
    const short8 b0 = *(const short8*)(g0p + j0 + 8 * q);
    const short8 b1 = *(const short8*)(g1p + j0 + 8 * q);
    acc0 = __builtin_amdgcn_mfma_f32_16x16x32_bf16(afrag, b0, acc0, 0, 0, 0);
    acc1 = __builtin_amdgcn_mfma_f32_16x16x32_bf16(afrag, b1, acc1, 0, 0, 0);
  }

  denom += __shfl_xor(denom, 16, 64);
  denom += __shfl_xor(denom, 32, 64);

  float* pb = pout + split * (N_NODES * OUTF);
  #pragma unroll
  for (int r = 0; r < 4; ++r) {
    const int irow = i0 + 4 * q + r;
    pb[irow * OUTF + hh * HF + il]      = acc0[r];
    pb[irow * OUTF + hh * HF + 16 + il] = acc1[r];
  }
  if (q == 0) pl[split * (N_NODES * NH) + (i0 + il) * NH + hh] = denom;
}

// ===================== Phase 5: reduce partials + normalize ================
__device__ __forceinline__ void phase_reduce(int bid, int tid,
    const float* __restrict__ pout, const float* __restrict__ pl,
    float* __restrict__ out) {
  const int T = bid * NTHR + tid;
  #pragma unroll
  for (int rep = 0; rep < 4; ++rep) {
    const int idx = T + rep * (NBLK * NTHR);   // covers 524288 outputs
    float s = 0.f;
    #pragma unroll
    for (int p = 0; p < JSPLIT; ++p) s += pout[p * (N_NODES * OUTF) + idx];
    const int ih = idx >> 5;
    float lsum = 0.f;
    #pragma unroll
    for (int p = 0; p < JSPLIT; ++p) lsum += pl[p * (N_NODES * NH) + ih];
    out[idx] = s / lsum;
  }
}

// ===================== Fused cooperative kernel ============================
__global__ __launch_bounds__(NTHR)
void gat_fused(const float* __restrict__ h, const int* __restrict__ adj,
               const float* __restrict__ W, const float* __restrict__ a,
               float* __restrict__ out, float* __restrict__ gp,
               float* __restrict__ pout, float* __restrict__ s_l,
               float* __restrict__ s_r_t, float* __restrict__ pl,
               unsigned* __restrict__ bits, short* __restrict__ gt,
               short* __restrict__ h_hi, short* __restrict__ h_lo,
               short* __restrict__ wt_hi, short* __restrict__ wt_lo) {
  cg::grid_group grid = cg::this_grid();
  const int bid = blockIdx.x, tid = threadIdx.x;
  phase_prep(bid, tid, h, adj, W, h_hi, h_lo, wt_hi, wt_lo, bits);
  grid.sync();
  phase_gemm(bid, tid, h_hi, h_lo, wt_hi, wt_lo, gp);
  grid.sync();
  phase_scores(bid, tid, gp, a, gt, s_l, s_r_t);
  grid.sync();
  phase_attn(bid, tid, bits, gt, s_l, s_r_t, pout, pl);
  phase_attn(bid + NBLK, tid, bits, gt, s_l, s_r_t, pout, pl);
  grid.sync();
  phase_reduce(bid, tid, pout, pl, out);
}

// ===================== Fallback standalone kernels =========================
__global__ __launch_bounds__(NTHR)
void k_prep(const float* h, const int* adj, const float* W, short* h_hi,
            short* h_lo, short* wt_hi, short* wt_lo, unsigned* bits) {
  phase_prep(blockIdx.x, threadIdx.x, h, adj, W, h_hi, h_lo, wt_hi, wt_lo, bits);
}
__global__ __launch_bounds__(NTHR)
void k_gemm(const short* h_hi, const short* h_lo, const short* wt_hi,
            const short* wt_lo, float* gp) {
  phase_gemm(blockIdx.x, threadIdx.x, h_hi, h_lo, wt_hi, wt_lo, gp);
}
__global__ __launch_bounds__(NTHR)
void k_scores(const float* gp, const float* a, short* gt, float* s_l,
              float* s_r_t) {
  phase_scores(blockIdx.x, threadIdx.x, gp, a, gt, s_l, s_r_t);
}
__global__ __launch_bounds__(NTHR)
void k_attn(const unsigned* bits, const short* gt, const float* s_l,
            const float* s_r_t, float* pout, float* pl) {
  phase_attn(blockIdx.x, threadIdx.x, bits, gt, s_l, s_r_t, pout, pl);
}
__global__ __launch_bounds__(NTHR)
void k_reduce(const float* pout, const float* pl, float* out) {
  phase_reduce(blockIdx.x, threadIdx.x, pout, pl, out);
}

// ---------------------------------------------------------------------------
extern "C" void kernel_launch(void* const* d_in, const int* in_sizes, int n_in,
                              void* d_out, int out_size, void* d_ws, size_t ws_size,
                              hipStream_t stream) {
  const float* h   = (const float*)d_in[0];
  const int*   adj = (const int*)d_in[1];
  const float* W   = (const float*)d_in[2];
  const float* a   = (const float*)d_in[3];
  float* out = (float*)d_out;

  float* gp    = (float*)d_ws;                       // 2048*256 fp32 (final g)
  float* pout  = gp + N_NODES * OUTF;                // JSPLIT * 2048*256
  float* s_l   = pout + JSPLIT * N_NODES * OUTF;     // 2048*8
  float* s_r_t = s_l + N_NODES * NH;                 // 8*2048
  float* pl    = s_r_t + NH * N_NODES;               // JSPLIT * 2048*8
  unsigned* bits = (unsigned*)(pl + JSPLIT * N_NODES * NH);   // 2048*64 u32
  short* gt    = (short*)(bits + N_NODES * 64);      // 8*32*2048 bf16
  short* h_hi  = gt + NH * HF * N_NODES;             // 2048*1024
  short* h_lo  = h_hi + N_NODES * IN_F;              // 2048*1024
  short* wt_hi = h_lo + N_NODES * IN_F;              // 256*1024
  short* wt_lo = wt_hi + OUTF * IN_F;                // 256*1024

  void* args[] = {(void*)&h, (void*)&adj, (void*)&W, (void*)&a, (void*)&out,
                  (void*)&gp, (void*)&pout, (void*)&s_l, (void*)&s_r_t,
                  (void*)&pl, (void*)&bits, (void*)&gt, (void*)&h_hi,
                  (void*)&h_lo, (void*)&wt_hi, (void*)&wt_lo};
  hipError_t err = hipLaunchCooperativeKernel((const void*)gat_fused,
                                              dim3(NBLK), dim3(NTHR), args, 0,
                                              stream);
  if (err != hipSuccess) {
    // Deterministic fallback: same phases, separate kernels.
    k_prep<<<NBLK, NTHR, 0, stream>>>(h, adj, W, h_hi, h_lo, wt_hi, wt_lo, bits);
    k_gemm<<<NBLK, NTHR, 0, stream>>>(h_hi, h_lo, wt_hi, wt_lo, gp);
    k_scores<<<NBLK, NTHR, 0, stream>>>(gp, a, gt, s_l, s_r_t);
    k_attn<<<NBLK * 2, NTHR, 0, stream>>>(bits, gt, s_l, s_r_t, pout, pl);
    k_reduce<<<NBLK, NTHR, 0, stream>>>(pout, pl, out);
  }
}

// Round 7
// 71.616 us; speedup vs baseline: 2.9161x; 2.9161x over previous
//
#include <hip/hip_runtime.h>
#include <hip/hip_bf16.h>
#include <math.h>

#define N_NODES 2048
#define IN_F    1024
#define NH      8
#define HF      32
#define OUTF    256   // NH*HF
#define JSPLIT  2
#define JR      (N_NODES / JSPLIT)   // 1024 j's per attention block

typedef __attribute__((ext_vector_type(8))) short short8;
typedef __attribute__((ext_vector_type(4))) short short4v;
typedef __attribute__((ext_vector_type(4))) float f32x4;

__device__ __forceinline__ short f2bf(float x) {   // fp32 -> bf16 bits, RNE
  unsigned u = __float_as_uint(x);
  return (short)((u + 0x7FFFu + ((u >> 16) & 1u)) >> 16);
}
__device__ __forceinline__ float bf2f(short b) {
  return __uint_as_float(((unsigned)(unsigned short)b) << 16);
}

// ---------------- Kernel 1: prep — split h/W to bf16 hi/lo, pack adj -------
__global__ __launch_bounds__(256)
void prep_kernel(const float* __restrict__ h, const int* __restrict__ adj,
                 const float* __restrict__ W, short* __restrict__ h_hi,
                 short* __restrict__ h_lo, short* __restrict__ wt_hi,
                 short* __restrict__ wt_lo, unsigned* __restrict__ bits) {
  const int T = blockIdx.x * 256 + threadIdx.x;   // 0 .. 262143
  {
    // h split: one 8-float unit per thread (2048*1024/8 = 262144)
    const float4 v0 = *(const float4*)(h + T * 8);
    const float4 v1 = *(const float4*)(h + T * 8 + 4);
    const float x[8] = {v0.x, v0.y, v0.z, v0.w, v1.x, v1.y, v1.z, v1.w};
    short8 hi, lo;
    #pragma unroll
    for (int j = 0; j < 8; ++j) {
      const short hb = f2bf(x[j]);
      hi[j] = hb;
      lo[j] = f2bf(x[j] - bf2f(hb));
    }
    *(short8*)(h_hi + T * 8) = hi;
    *(short8*)(h_lo + T * 8) = lo;
  }
  if (T < (OUTF * IN_F / 8)) {   // 32768 W units: transpose + split
    const int n = T >> 7, kg = T & 127;
    short8 hi, lo;
    #pragma unroll
    for (int j = 0; j < 8; ++j) {
      const float x = W[(kg * 8 + j) * OUTF + n];
      const short hb = f2bf(x);
      hi[j] = hb;
      lo[j] = f2bf(x - bf2f(hb));
    }
    *(short8*)(wt_hi + n * IN_F + kg * 8) = hi;
    *(short8*)(wt_lo + n * IN_F + kg * 8) = lo;
  }
  if (T < (N_NODES * 64)) {      // 131072 bit words
    const int4* p = (const int4*)(adj + (T >> 6) * N_NODES + (T & 63) * 32);
    unsigned wbits = 0;
    #pragma unroll
    for (int v = 0; v < 8; ++v) {
      const int4 x = p[v];
      wbits |= (x.x != 0 ? 1u : 0u) << (4 * v + 0);
      wbits |= (x.y != 0 ? 1u : 0u) << (4 * v + 1);
      wbits |= (x.z != 0 ? 1u : 0u) << (4 * v + 2);
      wbits |= (x.w != 0 ? 1u : 0u) << (4 * v + 3);
    }
    bits[T] = wbits;
  }
}

// ---------------- Kernel 2: g = h@W (split-bf16 MFMA) + scores + gt --------
// 256 blocks x 4 waves. Block = 32 rows x 2 heads; wave = 16 rows x 1 head.
// Wave emits: gt[h][f][node] bf16 (direct from acc), s_l, s_r_t (in-register
// dot with a_l/a_r + shfl reduce). No fp32 g buffer at all.
__global__ __launch_bounds__(256)
void gemm_scores_kernel(const short* __restrict__ h_hi, const short* __restrict__ h_lo,
                        const short* __restrict__ wt_hi, const short* __restrict__ wt_lo,
                        const float* __restrict__ a, short* __restrict__ gt,
                        float* __restrict__ s_l, float* __restrict__ s_r_t) {
  const int bid = blockIdx.x;
  const int mb = bid >> 2;             // 64 m-tiles of 32 rows
  const int nb = bid & 3;              // 4 head-pairs
  const int w = threadIdx.x >> 6;
  const int l = threadIdx.x & 63;
  const int il = l & 15, q = l >> 4;
  const int wm = w >> 1;               // m16 within the 32-row tile
  const int hh = nb * 2 + (w & 1);     // this wave's head
  const int rowb = mb * 32 + wm * 16;

  const short* ah  = h_hi + (rowb + il) * IN_F;
  const short* al  = h_lo + (rowb + il) * IN_F;
  const short* bh0 = wt_hi + (hh * HF + il) * IN_F;
  const short* bl0 = wt_lo + (hh * HF + il) * IN_F;
  const short* bh1 = bh0 + 16 * IN_F;
  const short* bl1 = bl0 + 16 * IN_F;

  f32x4 acc0 = {0.f, 0.f, 0.f, 0.f};   // cols h*32 + il
  f32x4 acc1 = {0.f, 0.f, 0.f, 0.f};   // cols h*32 + 16 + il
  #pragma unroll 4
  for (int k0 = 0; k0 < IN_F; k0 += 32) {
    const short8 a_h = *(const short8*)(ah + k0 + 8 * q);
    const short8 a_l = *(const short8*)(al + k0 + 8 * q);
    const short8 b_h0 = *(const short8*)(bh0 + k0 + 8 * q);
    const short8 b_l0 = *(const short8*)(bl0 + k0 + 8 * q);
    const short8 b_h1 = *(const short8*)(bh1 + k0 + 8 * q);
    const short8 b_l1 = *(const short8*)(bl1 + k0 + 8 * q);
    acc0 = __builtin_amdgcn_mfma_f32_16x16x32_bf16(a_h, b_h0, acc0, 0, 0, 0);
    acc0 = __builtin_amdgcn_mfma_f32_16x16x32_bf16(a_h, b_l0, acc0, 0, 0, 0);
    acc0 = __builtin_amdgcn_mfma_f32_16x16x32_bf16(a_l, b_h0, acc0, 0, 0, 0);
    acc1 = __builtin_amdgcn_mfma_f32_16x16x32_bf16(a_h, b_h1, acc1, 0, 0, 0);
    acc1 = __builtin_amdgcn_mfma_f32_16x16x32_bf16(a_h, b_l1, acc1, 0, 0, 0);
    acc1 = __builtin_amdgcn_mfma_f32_16x16x32_bf16(a_l, b_h1, acc1, 0, 0, 0);
  }

  // gt: D row = rowb + 4q + r, f = il (acc0) / 16+il (acc1). 4 nodes -> 8B.
  {
    short4v p0, p1;
    #pragma unroll
    for (int r = 0; r < 4; ++r) { p0[r] = f2bf(acc0[r]); p1[r] = f2bf(acc1[r]); }
    *(short4v*)(gt + (hh * HF + il) * N_NODES + rowb + 4 * q)      = p0;
    *(short4v*)(gt + (hh * HF + 16 + il) * N_NODES + rowb + 4 * q) = p1;
  }

  // scores: dot over f (reduce across the 16 il-lanes of this q-group)
  const float alv0 = a[il], alv1 = a[16 + il];
  const float arv0 = a[HF + il], arv1 = a[HF + 16 + il];
  float sl[4], sr[4];
  #pragma unroll
  for (int r = 0; r < 4; ++r) {
    sl[r] = acc0[r] * alv0 + acc1[r] * alv1;
    sr[r] = acc0[r] * arv0 + acc1[r] * arv1;
  }
  #pragma unroll
  for (int off = 8; off >= 1; off >>= 1) {
    #pragma unroll
    for (int r = 0; r < 4; ++r) {
      sl[r] += __shfl_xor(sl[r], off, 64);
      sr[r] += __shfl_xor(sr[r], off, 64);
    }
  }
  if (il == 0) {
    #pragma unroll
    for (int r = 0; r < 4; ++r) {
      const int node = rowb + 4 * q + r;
      s_l[node * NH + hh] = sl[r];
      s_r_t[hh * N_NODES + node] = sr[r];
    }
  }
}

// ---------------- Kernel 3: MFMA attention partials ------------------------
// grid (128 i-tiles, JSPLIT). 8 waves/block, wave = head. 16 i x 32 f per wave.
__global__ __launch_bounds__(512)
void attn_mfma_kernel(const unsigned* __restrict__ bits, const short* __restrict__ gt,
                      const float* __restrict__ s_l, const float* __restrict__ s_r_t,
                      float* __restrict__ pout, float* __restrict__ pl) {
  const int i0    = blockIdx.x * 16;
  const int split = blockIdx.y;
  const int tid   = threadIdx.x;
  const int hh = tid >> 6;
  const int l = tid & 63;
  const int il = l & 15;
  const int q  = l >> 4;

  const float slv = s_l[(i0 + il) * NH + hh];
  const unsigned* bitrow = bits + (i0 + il) * 64;
  const float* srh = s_r_t + hh * N_NODES;
  const short* g0p = gt + (hh * HF + il) * N_NODES;
  const short* g1p = gt + (hh * HF + 16 + il) * N_NODES;

  f32x4 acc0 = {0.f, 0.f, 0.f, 0.f};
  f32x4 acc1 = {0.f, 0.f, 0.f, 0.f};
  float denom = 0.f;

  const int jbase = split * JR;
  for (int j0 = jbase; j0 < jbase + JR; j0 += 32) {
    const unsigned word = bitrow[j0 >> 5];
    const float4 sra = *(const float4*)(srh + j0 + 8 * q);
    const float4 srb = *(const float4*)(srh + j0 + 8 * q + 4);
    const float sr_[8] = {sra.x, sra.y, sra.z, sra.w, srb.x, srb.y, srb.z, srb.w};
    short8 afrag;
    #pragma unroll
    for (int r = 0; r < 8; ++r) {
      float e = slv + sr_[r];
      e = fmaxf(e, 0.2f * e);                               // leaky relu
      const float wv = ((word >> (8 * q + r)) & 1u) ? __expf(e) : 0.f;
      const short wb = f2bf(wv);
      afrag[r] = wb;
      denom += bf2f(wb);   // denom consistent with bf16 numerator
    }
    const short8 b0 = *(const short8*)(g0p + j0 + 8 * q);
    const short8 b1 = *(const short8*)(g1p + j0 + 8 * q);
    acc0 = __builtin_amdgcn_mfma_f32_16x16x32_bf16(afrag, b0, acc0, 0, 0, 0);
    acc1 = __builtin_amdgcn_mfma_f32_16x16x32_bf16(afrag, b1, acc1, 0, 0, 0);
  }

  denom += __shfl_xor(denom, 16, 64);
  denom += __shfl_xor(denom, 32, 64);

  float* pb = pout + split * (N_NODES * OUTF);
  #pragma unroll
  for (int r = 0; r < 4; ++r) {
    const int irow = i0 + 4 * q + r;      // D: row = 4q+r, col = il
    pb[irow * OUTF + hh * HF + il]      = acc0[r];
    pb[irow * OUTF + hh * HF + 16 + il] = acc1[r];
  }
  if (q == 0) pl[split * (N_NODES * NH) + (i0 + il) * NH + hh] = denom;
}

// ---------------- Kernel 4: sum partials, normalize (float4) ---------------
__global__ __launch_bounds__(256)
void reduce_kernel(const float* __restrict__ pout, const float* __restrict__ pl,
                   float* __restrict__ out) {
  const int idx4 = (blockIdx.x * 256 + threadIdx.x) * 4;  // 524288 outputs
  float4 s = *(const float4*)(pout + idx4);
  #pragma unroll
  for (int p = 1; p < JSPLIT; ++p) {
    const float4 u = *(const float4*)(pout + p * (N_NODES * OUTF) + idx4);
    s.x += u.x; s.y += u.y; s.z += u.z; s.w += u.w;
  }
  const int ih = idx4 >> 5;   // node*8 + h (same for all 4 f's)
  float lsum = 0.f;
  #pragma unroll
  for (int p = 0; p < JSPLIT; ++p) lsum += pl[p * (N_NODES * NH) + ih];
  const float inv = 1.0f / lsum;
  s.x *= inv; s.y *= inv; s.z *= inv; s.w *= inv;
  *(float4*)(out + idx4) = s;
}

// ---------------------------------------------------------------------------
extern "C" void kernel_launch(void* const* d_in, const int* in_sizes, int n_in,
                              void* d_out, int out_size, void* d_ws, size_t ws_size,
                              hipStream_t stream) {
  const float* h   = (const float*)d_in[0];
  const int*   adj = (const int*)d_in[1];
  const float* W   = (const float*)d_in[2];
  const float* a   = (const float*)d_in[3];
  float* out = (float*)d_out;

  float* pout  = (float*)d_ws;                       // JSPLIT * 2048*256
  float* s_l   = pout + JSPLIT * N_NODES * OUTF;     // 2048*8
  float* s_r_t = s_l + N_NODES * NH;                 // 8*2048
  float* pl    = s_r_t + NH * N_NODES;               // JSPLIT * 2048*8
  unsigned* bits = (unsigned*)(pl + JSPLIT * N_NODES * NH);   // 2048*64 u32
  short* gt    = (short*)(bits + N_NODES * 64);      // 8*32*2048 bf16
  short* h_hi  = gt + NH * HF * N_NODES;             // 2048*1024
  short* h_lo  = h_hi + N_NODES * IN_F;              // 2048*1024
  short* wt_hi = h_lo + N_NODES * IN_F;              // 256*1024
  short* wt_lo = wt_hi + OUTF * IN_F;                // 256*1024

  prep_kernel<<<1024, 256, 0, stream>>>(h, adj, W, h_hi, h_lo, wt_hi, wt_lo, bits);
  gemm_scores_kernel<<<256, 256, 0, stream>>>(h_hi, h_lo, wt_hi, wt_lo, a, gt, s_l, s_r_t);
  attn_mfma_kernel<<<dim3(N_NODES / 16, JSPLIT), 512, 0, stream>>>(bits, gt, s_l, s_r_t, pout, pl);
  reduce_kernel<<<(N_NODES * OUTF / 4) / 256, 256, 0, stream>>>(pout, pl, out);
}